// Round 7
// baseline (822.925 us; speedup 1.0000x reference)
//
#include <hip/hip_runtime.h>

#define NC 128      // channels
#define NB 8        // batch
#define CPB 32      // channels per block
#define R 4         // consecutive j outputs per thread
#define JT (8 * R)  // j-tile width per block (threadIdx.y covers 8 runs)

// ---------------------------------------------------------------------------
// LL-only Haar downsample: P (NB, 2h, 2w, NC) -> out (NB, h, w, NC)
// ---------------------------------------------------------------------------
__global__ __launch_bounds__(256) void k_haar_ll(
    const float* __restrict__ P, float* __restrict__ out, int h, int w)
{
    int idx = blockIdx.x * blockDim.x + threadIdx.x;
    int total = NB * h * w * (NC / 4);
    if (idx >= total) return;
    int cq = idx & (NC / 4 - 1);
    int t  = idx / (NC / 4);
    int j  = t % w; t /= w;
    int i  = t % h;
    int b  = t / h;
    size_t W2C  = (size_t)(2 * w) * NC;
    size_t base = (((size_t)b * (2 * h) + 2 * i) * (2 * w) + 2 * j) * NC + cq * 4;
    float4 A  = *(const float4*)(P + base);
    float4 Bv = *(const float4*)(P + base + NC);
    float4 Cv = *(const float4*)(P + base + W2C);
    float4 Dv = *(const float4*)(P + base + W2C + NC);
    float4 r;
    r.x = (A.x + Bv.x + Cv.x + Dv.x) * 0.5f;
    r.y = (A.y + Bv.y + Cv.y + Dv.y) * 0.5f;
    r.z = (A.z + Bv.z + Cv.z + Dv.z) * 0.5f;
    r.w = (A.w + Bv.w + Cv.w + Dv.w) * 0.5f;
    *(float4*)(out + (size_t)idx * 4) = r;
}

// ---------------------------------------------------------------------------
// Fused conv-on-haar-subbands + inverse (+ base depthwise for level 0).
// R=4 sliding window; per-thread interior/edge split:
//  - interior: direct immediate-offset loads, no clamps/masks (no coff/cmask
//    arrays -> fits the <=128 VGPR occupancy band; R6's 132 VGPR fell off
//    the cliff: occupancy 34% -> 11.7%).
//  - edge (ja<2 or ja>w-R-2): compact per-tap loop, weights straight from
//    LDS, same accumulators -> shared epilogue.
// __launch_bounds__(256,4) = 128-VGPR cap as a safety net (need ~120).
// blockDim = (32, 8). grid = ((w/JT)*4, h, NB). blockIdx.x = jtile*4 + cg.
// ---------------------------------------------------------------------------
#define WL(s, t)  wl[((s) * 25 + (t)) * CPB + tc]
#define WB(m, n)  wbase[((m) * 5 + (n)) * CPB + tc]

template <bool BASE>
__global__ __launch_bounds__(256, 4) void k_convinv(
    const float* __restrict__ P, const float* __restrict__ nll,
    const float* __restrict__ wk, const float* __restrict__ wsc,
    const float* __restrict__ bk, const float* __restrict__ bb,
    const float* __restrict__ bs, float* __restrict__ out,
    int h, int w)
{
    extern __shared__ float lds[];
    float* wl     = lds;               // [4][25][CPB]
    float* wbase  = wl + 4 * 25 * CPB; // [25][CPB]   (BASE)
    float* bscale = wbase + 25 * CPB;  // [CPB]       (BASE)
    float* bbias  = bscale + CPB;      // [CPB]       (BASE)

    const int cg    = blockIdx.x & 3;
    const int jtile = blockIdx.x >> 2;
    const int c0    = cg * CPB;
    const int tid   = threadIdx.x + threadIdx.y * 32;

    for (int u = tid; u < 4 * 25 * CPB; u += 256) {
        int tcc = u & (CPB - 1);
        int st  = u / CPB;
        int t   = st % 25;
        int s   = st / 25;
        wl[u] = 0.5f * wsc[(c0 + tcc) * 4 + s] * wk[t * (4 * NC) + (c0 + tcc) * 4 + s];
    }
    if (BASE) {
        for (int u = tid; u < 25 * CPB; u += 256) {
            int tcc = u & (CPB - 1);
            int t   = u / CPB;
            wbase[u] = bk[t * NC + c0 + tcc];
        }
        if (tid < CPB) { bscale[tid] = bs[c0 + tid]; bbias[tid] = bb[c0 + tid]; }
    }
    __syncthreads();

    const int tc = threadIdx.x;
    const int c  = c0 + tc;
    const int b  = blockIdx.z;
    const int i  = blockIdx.y;
    const int ja = jtile * JT + threadIdx.y * R;   // first output j of thread
    const int PH = 2 * h;
    const size_t rowC = (size_t)(2 * w) * NC;

    float acc0[R], acc1[R], acc2[R], acc3[R];
    float bb00[R], bb01[R], bb10[R], bb11[R];
    #pragma unroll
    for (int s = 0; s < R; ++s) {
        acc0[s] = acc1[s] = acc2[s] = acc3[s] = 0.f;
        bb00[s] = bb01[s] = bb10[s] = bb11[s] = 0.f;
    }

    const bool interior = (ja >= 2) && (ja <= w - R - 2);

    if (interior) {
        // ------------------------- fast path (no masks) -------------------
        #pragma unroll
        for (int ky = 0; ky < 5; ++ky) {
            int y = i + ky - 2;
            if (y < 0 || y >= h) continue;          // block-uniform

            float w0[5], w1[5], w2[5], w3[5];
            #pragma unroll
            for (int kx = 0; kx < 5; ++kx) {
                const int t = ky * 5 + kx;
                w0[kx] = WL(0, t); w1[kx] = WL(1, t);
                w2[kx] = WL(2, t); w3[kx] = WL(3, t);
            }
            float wbr[3][5];
            if (BASE && ky >= 1 && ky <= 3) {
                #pragma unroll
                for (int n = 0; n < 5; ++n) {
                    if (ky >= 2) wbr[0][n] = WB(2 * ky - 3, n);
                    wbr[1][n] = WB(2 * ky - 2, n);
                    if (ky <= 2) wbr[2][n] = WB(2 * ky - 1, n);
                }
            }

            const float* pA0 = P + ((size_t)b * PH + 2 * y) * rowC + c
                                 + (size_t)(ja - 2) * (2 * NC);
            const float* pC0 = pA0 + rowC;
            #pragma unroll
            for (int q = 0; q < R + 4; ++q) {
                float A  = pA0[q * 2 * NC];
                float Bv = pA0[q * 2 * NC + NC];
                float Cv = pC0[q * 2 * NC];
                float Dv = pC0[q * 2 * NC + NC];
                float sA = A + Bv, sC = Cv + Dv;
                float dA = A - Bv, dC = Cv - Dv;
                float s0 = sA + sC, s1 = sA - sC, s2 = dA + dC, s3 = dA - dC;
                #pragma unroll
                for (int s = 0; s < R; ++s) {
                    const int kx = q - s;
                    if (kx < 0 || kx > 4) continue;
                    acc0[s] += s0 * w0[kx];
                    acc1[s] += s1 * w1[kx];
                    acc2[s] += s2 * w2[kx];
                    acc3[s] += s3 * w3[kx];
                    if (BASE && ky >= 1 && ky <= 3 && kx >= 1 && kx <= 3) {
                        bb00[s] += A * wbr[1][2 * kx - 2];
                        if (kx >= 2)            bb01[s] += A  * wbr[1][2 * kx - 3];
                        if (ky >= 2)            bb10[s] += A  * wbr[0][2 * kx - 2];
                        if (ky >= 2 && kx >= 2) bb11[s] += A  * wbr[0][2 * kx - 3];
                        if (kx <= 2)            bb00[s] += Bv * wbr[1][2 * kx - 1];
                                                bb01[s] += Bv * wbr[1][2 * kx - 2];
                        if (ky >= 2 && kx <= 2) bb10[s] += Bv * wbr[0][2 * kx - 1];
                        if (ky >= 2)            bb11[s] += Bv * wbr[0][2 * kx - 2];
                        if (ky <= 2)            bb00[s] += Cv * wbr[2][2 * kx - 2];
                        if (ky <= 2 && kx >= 2) bb01[s] += Cv * wbr[2][2 * kx - 3];
                                                bb10[s] += Cv * wbr[1][2 * kx - 2];
                        if (kx >= 2)            bb11[s] += Cv * wbr[1][2 * kx - 3];
                        if (ky <= 2 && kx <= 2) bb00[s] += Dv * wbr[2][2 * kx - 1];
                        if (ky <= 2)            bb01[s] += Dv * wbr[2][2 * kx - 2];
                        if (kx <= 2)            bb10[s] += Dv * wbr[1][2 * kx - 1];
                                                bb11[s] += Dv * wbr[1][2 * kx - 2];
                    }
                }
            }
        }
    } else {
        // ------------------------- edge slow path -------------------------
        #pragma unroll
        for (int s = 0; s < R; ++s) {
            int j = ja + s;
            #pragma unroll
            for (int ky = 0; ky < 5; ++ky) {
                int y = i + ky - 2;
                if (y < 0 || y >= h) continue;
                const float* prA = P + ((size_t)b * PH + 2 * y) * rowC + c;
                const float* prC = prA + rowC;
                #pragma unroll
                for (int kx = 0; kx < 5; ++kx) {
                    int xq = j + kx - 2;
                    if (xq < 0 || xq >= w) continue;
                    const float* pA = prA + (size_t)xq * (2 * NC);
                    const float* pC = prC + (size_t)xq * (2 * NC);
                    float A  = pA[0];
                    float Bv = pA[NC];
                    float Cv = pC[0];
                    float Dv = pC[NC];
                    float sA = A + Bv, sC = Cv + Dv;
                    float dA = A - Bv, dC = Cv - Dv;
                    const int t = ky * 5 + kx;
                    acc0[s] += (sA + sC) * WL(0, t);
                    acc1[s] += (sA - sC) * WL(1, t);
                    acc2[s] += (dA + dC) * WL(2, t);
                    acc3[s] += (dA - dC) * WL(3, t);
                    if (BASE && ky >= 1 && ky <= 3 && kx >= 1 && kx <= 3) {
                        bb00[s] += A * WB(2 * ky - 2, 2 * kx - 2);
                        if (kx >= 2)            bb01[s] += A  * WB(2 * ky - 2, 2 * kx - 3);
                        if (ky >= 2)            bb10[s] += A  * WB(2 * ky - 3, 2 * kx - 2);
                        if (ky >= 2 && kx >= 2) bb11[s] += A  * WB(2 * ky - 3, 2 * kx - 3);
                        if (kx <= 2)            bb00[s] += Bv * WB(2 * ky - 2, 2 * kx - 1);
                                                bb01[s] += Bv * WB(2 * ky - 2, 2 * kx - 2);
                        if (ky >= 2 && kx <= 2) bb10[s] += Bv * WB(2 * ky - 3, 2 * kx - 1);
                        if (ky >= 2)            bb11[s] += Bv * WB(2 * ky - 3, 2 * kx - 2);
                        if (ky <= 2)            bb00[s] += Cv * WB(2 * ky - 1, 2 * kx - 2);
                        if (ky <= 2 && kx >= 2) bb01[s] += Cv * WB(2 * ky - 1, 2 * kx - 3);
                                                bb10[s] += Cv * WB(2 * ky - 2, 2 * kx - 2);
                        if (kx >= 2)            bb11[s] += Cv * WB(2 * ky - 2, 2 * kx - 3);
                        if (ky <= 2 && kx <= 2) bb00[s] += Dv * WB(2 * ky - 1, 2 * kx - 1);
                        if (ky <= 2)            bb01[s] += Dv * WB(2 * ky - 1, 2 * kx - 2);
                        if (kx <= 2)            bb10[s] += Dv * WB(2 * ky - 2, 2 * kx - 1);
                                                bb11[s] += Dv * WB(2 * ky - 2, 2 * kx - 2);
                    }
                }
            }
        }
    }

    // ------------------------------ epilogue ------------------------------
    #pragma unroll
    for (int s = 0; s < R; ++s) {
        int j = ja + s;
        float a0 = acc0[s];
        if (nll) a0 += nll[(((size_t)b * h + i) * w + j) * NC + c];
        float av = (a0 + acc1[s] + acc2[s] + acc3[s]) * 0.5f;
        float bv = (a0 + acc1[s] - acc2[s] - acc3[s]) * 0.5f;
        float cv = (a0 - acc1[s] + acc2[s] - acc3[s]) * 0.5f;
        float dv = (a0 - acc1[s] - acc2[s] + acc3[s]) * 0.5f;

        size_t ob = ((size_t)b * PH + 2 * i) * rowC + (size_t)(2 * j) * NC + c;
        if (BASE) {
            float sc = bscale[tc], bi = bbias[tc];
            out[ob]             = sc * (bb00[s] + bi) + av;
            out[ob + NC]        = sc * (bb01[s] + bi) + bv;
            out[ob + rowC]      = sc * (bb10[s] + bi) + cv;
            out[ob + rowC + NC] = sc * (bb11[s] + bi) + dv;
        } else {
            out[ob]             = av;
            out[ob + NC]        = bv;
            out[ob + rowC]      = cv;
            out[ob + rowC + NC] = dv;
        }
    }
}

// ---------------------------------------------------------------------------
extern "C" void kernel_launch(void* const* d_in, const int* in_sizes, int n_in,
                              void* d_out, int out_size, void* d_ws, size_t ws_size,
                              hipStream_t stream)
{
    const float* x  = (const float*)d_in[0];
    const float* bk = (const float*)d_in[1];
    const float* bb = (const float*)d_in[2];
    const float* bs = (const float*)d_in[3];
    const float* wk[3];
    const float* wv[3];
    if (n_in >= 10) {
        for (int i = 0; i < 3; ++i) {
            wk[i] = (const float*)d_in[4 + i];
            wv[i] = (const float*)d_in[7 + i];
        }
    } else {
        const float* wkc = (const float*)d_in[4];
        const float* wvc = (const float*)d_in[5];
        for (int i = 0; i < 3; ++i) {
            wk[i] = wkc + (size_t)i * 25 * 4 * NC;
            wv[i] = wvc + (size_t)i * 4 * NC;
        }
    }
    float* out = (float*)d_out;

    // Dead-before-final intermediates live inside d_out (fully rewritten by
    // the final kernel). r1 (read during final pass) lives in d_ws.
    float* ll0 = out;                       // (8,128,128,128)
    float* ll1 = out + 16777216;            // (8, 64, 64,128)
    float* r2  = out + 16777216 + 4194304;  // (8, 64, 64,128)
    float* r1  = (float*)d_ws;              // (8,128,128,128) = 64 MiB

    // 1) x -> ll0
    {
        int total = NB * 128 * 128 * (NC / 4);
        k_haar_ll<<<(total + 255) / 256, 256, 0, stream>>>(x, ll0, 128, 128);
    }
    // 2) ll0 -> ll1
    {
        int total = NB * 64 * 64 * (NC / 4);
        k_haar_ll<<<(total + 255) / 256, 256, 0, stream>>>(ll0, ll1, 64, 64);
    }

    size_t lds_nb = (size_t)(4 * 25 * CPB) * sizeof(float);                      // 12800 B
    size_t lds_b  = (size_t)(4 * 25 * CPB + 25 * CPB + 2 * CPB) * sizeof(float); // 16256 B
    dim3 blk(32, 8);

    // 3) level 2: ll1 -> r2   (coeff grid 32x32, JT=32 -> 1 jtile)
    k_convinv<false><<<dim3((32 / JT) * 4, 32, NB), blk, lds_nb, stream>>>(
        ll1, nullptr, wk[2], wv[2], nullptr, nullptr, nullptr, r2, 32, 32);

    // 4) level 1: ll0 (+r2) -> r1   (coeff grid 64x64)
    k_convinv<false><<<dim3((64 / JT) * 4, 64, NB), blk, lds_nb, stream>>>(
        ll0, r2, wk[1], wv[1], nullptr, nullptr, nullptr, r1, 64, 64);

    // 5) level 0: x (+r1) + base path -> d_out   (coeff grid 128x128)
    k_convinv<true><<<dim3((128 / JT) * 4, 128, NB), blk, lds_b, stream>>>(
        x, r1, wk[0], wv[0], bk, bb, bs, out, 128, 128);
}

// Round 8
// 804.748 us; speedup vs baseline: 1.0226x; 1.0226x over previous
//
#include <hip/hip_runtime.h>

#define NC 128      // channels
#define NB 8        // batch
#define CPB 32      // channels per block
#define R 2         // consecutive j outputs per thread
#define JT (8 * R)  // j-tile width per block (threadIdx.y covers 8 runs)

// ---------------------------------------------------------------------------
// LL-only Haar downsample: P (NB, 2h, 2w, NC) -> out (NB, h, w, NC)
// ---------------------------------------------------------------------------
__global__ __launch_bounds__(256) void k_haar_ll(
    const float* __restrict__ P, float* __restrict__ out, int h, int w)
{
    int idx = blockIdx.x * blockDim.x + threadIdx.x;
    int total = NB * h * w * (NC / 4);
    if (idx >= total) return;
    int cq = idx & (NC / 4 - 1);
    int t  = idx / (NC / 4);
    int j  = t % w; t /= w;
    int i  = t % h;
    int b  = t / h;
    size_t W2C  = (size_t)(2 * w) * NC;
    size_t base = (((size_t)b * (2 * h) + 2 * i) * (2 * w) + 2 * j) * NC + cq * 4;
    float4 A  = *(const float4*)(P + base);
    float4 Bv = *(const float4*)(P + base + NC);
    float4 Cv = *(const float4*)(P + base + W2C);
    float4 Dv = *(const float4*)(P + base + W2C + NC);
    float4 r;
    r.x = (A.x + Bv.x + Cv.x + Dv.x) * 0.5f;
    r.y = (A.y + Bv.y + Cv.y + Dv.y) * 0.5f;
    r.z = (A.z + Bv.z + Cv.z + Dv.z) * 0.5f;
    r.w = (A.w + Bv.w + Cv.w + Dv.w) * 0.5f;
    *(float4*)(out + (size_t)idx * 4) = r;
}

// ---------------------------------------------------------------------------
// Fused conv-on-haar-subbands + inverse (+ base depthwise for level 0).
// H, W are TEMPLATE params: all strides/offsets are compile-time constants,
// so interior-path loads fold into immediate offsets off per-row bases
// (kills the per-load 64-bit address arithmetic that dominated R5's issue).
// Interior/edge split per thread; R=2; NO launch-bounds cap (caps caused
// spill disasters in R4/R7: WRITE_SIZE 262MB -> 707MB..2.4GB).
// blockDim = (32, 8). grid = ((W/JT)*4, H, NB). blockIdx.x = jtile*4 + cg.
// ---------------------------------------------------------------------------
#define WL(s, t)  wl[((s) * 25 + (t)) * CPB + tc]
#define WB(m, n)  wbase[((m) * 5 + (n)) * CPB + tc]

template <bool BASE, int H, int W>
__global__ __launch_bounds__(256) void k_convinv(
    const float* __restrict__ P, const float* __restrict__ nll,
    const float* __restrict__ wk, const float* __restrict__ wsc,
    const float* __restrict__ bk, const float* __restrict__ bb,
    const float* __restrict__ bs, float* __restrict__ out)
{
    extern __shared__ float lds[];
    float* wl     = lds;               // [4][25][CPB]
    float* wbase  = wl + 4 * 25 * CPB; // [25][CPB]   (BASE)
    float* bscale = wbase + 25 * CPB;  // [CPB]       (BASE)
    float* bbias  = bscale + CPB;      // [CPB]       (BASE)

    const int cg    = blockIdx.x & 3;
    const int jtile = blockIdx.x >> 2;
    const int c0    = cg * CPB;
    const int tid   = threadIdx.x + threadIdx.y * 32;

    for (int u = tid; u < 4 * 25 * CPB; u += 256) {
        int tcc = u & (CPB - 1);
        int st  = u / CPB;
        int t   = st % 25;
        int s   = st / 25;
        wl[u] = 0.5f * wsc[(c0 + tcc) * 4 + s] * wk[t * (4 * NC) + (c0 + tcc) * 4 + s];
    }
    if (BASE) {
        for (int u = tid; u < 25 * CPB; u += 256) {
            int tcc = u & (CPB - 1);
            int t   = u / CPB;
            wbase[u] = bk[t * NC + c0 + tcc];
        }
        if (tid < CPB) { bscale[tid] = bs[c0 + tid]; bbias[tid] = bb[c0 + tid]; }
    }
    __syncthreads();

    const int tc = threadIdx.x;
    const int c  = c0 + tc;
    const int b  = blockIdx.z;
    const int i  = blockIdx.y;
    const int ja = jtile * JT + threadIdx.y * R;   // first output j of thread
    constexpr int ROWC = 2 * W * NC;               // parent row stride (elems)

    float acc0[R], acc1[R], acc2[R], acc3[R];
    float bb00[R], bb01[R], bb10[R], bb11[R];
    #pragma unroll
    for (int s = 0; s < R; ++s) {
        acc0[s] = acc1[s] = acc2[s] = acc3[s] = 0.f;
        bb00[s] = bb01[s] = bb10[s] = bb11[s] = 0.f;
    }

    const bool interior = (ja >= 2) && (ja <= W - R - 2);

    if (interior) {
        // ------------------------- fast path (no masks) -------------------
        #pragma unroll
        for (int ky = 0; ky < 5; ++ky) {
            int y = i + ky - 2;
            if (y < 0 || y >= H) continue;          // block-uniform

            float w0[5], w1[5], w2[5], w3[5];
            #pragma unroll
            for (int kx = 0; kx < 5; ++kx) {
                const int t = ky * 5 + kx;
                w0[kx] = WL(0, t); w1[kx] = WL(1, t);
                w2[kx] = WL(2, t); w3[kx] = WL(3, t);
            }
            float wbr[3][5];
            if (BASE && ky >= 1 && ky <= 3) {
                #pragma unroll
                for (int n = 0; n < 5; ++n) {
                    if (ky >= 2) wbr[0][n] = WB(2 * ky - 3, n);
                    wbr[1][n] = WB(2 * ky - 2, n);
                    if (ky <= 2) wbr[2][n] = WB(2 * ky - 1, n);
                }
            }

            // Compile-time strides: loads below are base + immediate.
            const float* pA0 = P + (size_t)(b * 2 * H + 2 * y) * ROWC
                                 + (ja - 2) * (2 * NC) + c;
            const float* pC0 = pA0 + ROWC;
            #pragma unroll
            for (int q = 0; q < R + 4; ++q) {
                float A  = pA0[q * 2 * NC];
                float Bv = pA0[q * 2 * NC + NC];
                float Cv = pC0[q * 2 * NC];
                float Dv = pC0[q * 2 * NC + NC];
                float sA = A + Bv, sC = Cv + Dv;
                float dA = A - Bv, dC = Cv - Dv;
                float s0 = sA + sC, s1 = sA - sC, s2 = dA + dC, s3 = dA - dC;
                #pragma unroll
                for (int s = 0; s < R; ++s) {
                    const int kx = q - s;
                    if (kx < 0 || kx > 4) continue;
                    acc0[s] += s0 * w0[kx];
                    acc1[s] += s1 * w1[kx];
                    acc2[s] += s2 * w2[kx];
                    acc3[s] += s3 * w3[kx];
                    if (BASE && ky >= 1 && ky <= 3 && kx >= 1 && kx <= 3) {
                        bb00[s] += A * wbr[1][2 * kx - 2];
                        if (kx >= 2)            bb01[s] += A  * wbr[1][2 * kx - 3];
                        if (ky >= 2)            bb10[s] += A  * wbr[0][2 * kx - 2];
                        if (ky >= 2 && kx >= 2) bb11[s] += A  * wbr[0][2 * kx - 3];
                        if (kx <= 2)            bb00[s] += Bv * wbr[1][2 * kx - 1];
                                                bb01[s] += Bv * wbr[1][2 * kx - 2];
                        if (ky >= 2 && kx <= 2) bb10[s] += Bv * wbr[0][2 * kx - 1];
                        if (ky >= 2)            bb11[s] += Bv * wbr[0][2 * kx - 2];
                        if (ky <= 2)            bb00[s] += Cv * wbr[2][2 * kx - 2];
                        if (ky <= 2 && kx >= 2) bb01[s] += Cv * wbr[2][2 * kx - 3];
                                                bb10[s] += Cv * wbr[1][2 * kx - 2];
                        if (kx >= 2)            bb11[s] += Cv * wbr[1][2 * kx - 3];
                        if (ky <= 2 && kx <= 2) bb00[s] += Dv * wbr[2][2 * kx - 1];
                        if (ky <= 2)            bb01[s] += Dv * wbr[2][2 * kx - 2];
                        if (kx <= 2)            bb10[s] += Dv * wbr[1][2 * kx - 1];
                                                bb11[s] += Dv * wbr[1][2 * kx - 2];
                    }
                }
            }
        }
    } else {
        // ------------------------- edge slow path -------------------------
        #pragma unroll
        for (int s = 0; s < R; ++s) {
            int j = ja + s;
            #pragma unroll
            for (int ky = 0; ky < 5; ++ky) {
                int y = i + ky - 2;
                if (y < 0 || y >= H) continue;
                const float* prA = P + (size_t)(b * 2 * H + 2 * y) * ROWC + c;
                const float* prC = prA + ROWC;
                #pragma unroll
                for (int kx = 0; kx < 5; ++kx) {
                    int xq = j + kx - 2;
                    if (xq < 0 || xq >= W) continue;
                    const float* pA = prA + xq * (2 * NC);
                    const float* pC = prC + xq * (2 * NC);
                    float A  = pA[0];
                    float Bv = pA[NC];
                    float Cv = pC[0];
                    float Dv = pC[NC];
                    float sA = A + Bv, sC = Cv + Dv;
                    float dA = A - Bv, dC = Cv - Dv;
                    const int t = ky * 5 + kx;
                    acc0[s] += (sA + sC) * WL(0, t);
                    acc1[s] += (sA - sC) * WL(1, t);
                    acc2[s] += (dA + dC) * WL(2, t);
                    acc3[s] += (dA - dC) * WL(3, t);
                    if (BASE && ky >= 1 && ky <= 3 && kx >= 1 && kx <= 3) {
                        bb00[s] += A * WB(2 * ky - 2, 2 * kx - 2);
                        if (kx >= 2)            bb01[s] += A  * WB(2 * ky - 2, 2 * kx - 3);
                        if (ky >= 2)            bb10[s] += A  * WB(2 * ky - 3, 2 * kx - 2);
                        if (ky >= 2 && kx >= 2) bb11[s] += A  * WB(2 * ky - 3, 2 * kx - 3);
                        if (kx <= 2)            bb00[s] += Bv * WB(2 * ky - 2, 2 * kx - 1);
                                                bb01[s] += Bv * WB(2 * ky - 2, 2 * kx - 2);
                        if (ky >= 2 && kx <= 2) bb10[s] += Bv * WB(2 * ky - 3, 2 * kx - 1);
                        if (ky >= 2)            bb11[s] += Bv * WB(2 * ky - 3, 2 * kx - 2);
                        if (ky <= 2)            bb00[s] += Cv * WB(2 * ky - 1, 2 * kx - 2);
                        if (ky <= 2 && kx >= 2) bb01[s] += Cv * WB(2 * ky - 1, 2 * kx - 3);
                                                bb10[s] += Cv * WB(2 * ky - 2, 2 * kx - 2);
                        if (kx >= 2)            bb11[s] += Cv * WB(2 * ky - 2, 2 * kx - 3);
                        if (ky <= 2 && kx <= 2) bb00[s] += Dv * WB(2 * ky - 1, 2 * kx - 1);
                        if (ky <= 2)            bb01[s] += Dv * WB(2 * ky - 1, 2 * kx - 2);
                        if (kx <= 2)            bb10[s] += Dv * WB(2 * ky - 2, 2 * kx - 1);
                                                bb11[s] += Dv * WB(2 * ky - 2, 2 * kx - 2);
                    }
                }
            }
        }
    }

    // ------------------------------ epilogue ------------------------------
    #pragma unroll
    for (int s = 0; s < R; ++s) {
        int j = ja + s;
        float a0 = acc0[s];
        if (nll) a0 += nll[((size_t)(b * H + i) * W + j) * NC + c];
        float av = (a0 + acc1[s] + acc2[s] + acc3[s]) * 0.5f;
        float bv = (a0 + acc1[s] - acc2[s] - acc3[s]) * 0.5f;
        float cv = (a0 - acc1[s] + acc2[s] - acc3[s]) * 0.5f;
        float dv = (a0 - acc1[s] - acc2[s] + acc3[s]) * 0.5f;

        size_t ob = (size_t)(b * 2 * H + 2 * i) * (2 * W * NC) + (2 * j) * NC + c;
        if (BASE) {
            float sc = bscale[tc], bi = bbias[tc];
            out[ob]                  = sc * (bb00[s] + bi) + av;
            out[ob + NC]             = sc * (bb01[s] + bi) + bv;
            out[ob + 2 * W * NC]     = sc * (bb10[s] + bi) + cv;
            out[ob + 2 * W * NC + NC] = sc * (bb11[s] + bi) + dv;
        } else {
            out[ob]                  = av;
            out[ob + NC]             = bv;
            out[ob + 2 * W * NC]     = cv;
            out[ob + 2 * W * NC + NC] = dv;
        }
    }
}

// ---------------------------------------------------------------------------
extern "C" void kernel_launch(void* const* d_in, const int* in_sizes, int n_in,
                              void* d_out, int out_size, void* d_ws, size_t ws_size,
                              hipStream_t stream)
{
    const float* x  = (const float*)d_in[0];
    const float* bk = (const float*)d_in[1];
    const float* bb = (const float*)d_in[2];
    const float* bs = (const float*)d_in[3];
    const float* wk[3];
    const float* wv[3];
    if (n_in >= 10) {
        for (int i = 0; i < 3; ++i) {
            wk[i] = (const float*)d_in[4 + i];
            wv[i] = (const float*)d_in[7 + i];
        }
    } else {
        const float* wkc = (const float*)d_in[4];
        const float* wvc = (const float*)d_in[5];
        for (int i = 0; i < 3; ++i) {
            wk[i] = wkc + (size_t)i * 25 * 4 * NC;
            wv[i] = wvc + (size_t)i * 4 * NC;
        }
    }
    float* out = (float*)d_out;

    // Dead-before-final intermediates live inside d_out (fully rewritten by
    // the final kernel). r1 (read during final pass) lives in d_ws.
    float* ll0 = out;                       // (8,128,128,128)
    float* ll1 = out + 16777216;            // (8, 64, 64,128)
    float* r2  = out + 16777216 + 4194304;  // (8, 64, 64,128)
    float* r1  = (float*)d_ws;              // (8,128,128,128) = 64 MiB

    // 1) x -> ll0
    {
        int total = NB * 128 * 128 * (NC / 4);
        k_haar_ll<<<(total + 255) / 256, 256, 0, stream>>>(x, ll0, 128, 128);
    }
    // 2) ll0 -> ll1
    {
        int total = NB * 64 * 64 * (NC / 4);
        k_haar_ll<<<(total + 255) / 256, 256, 0, stream>>>(ll0, ll1, 64, 64);
    }

    size_t lds_nb = (size_t)(4 * 25 * CPB) * sizeof(float);                      // 12800 B
    size_t lds_b  = (size_t)(4 * 25 * CPB + 25 * CPB + 2 * CPB) * sizeof(float); // 16256 B
    dim3 blk(32, 8);

    // 3) level 2: ll1 -> r2   (coeff grid 32x32)
    k_convinv<false, 32, 32><<<dim3((32 / JT) * 4, 32, NB), blk, lds_nb, stream>>>(
        ll1, nullptr, wk[2], wv[2], nullptr, nullptr, nullptr, r2);

    // 4) level 1: ll0 (+r2) -> r1   (coeff grid 64x64)
    k_convinv<false, 64, 64><<<dim3((64 / JT) * 4, 64, NB), blk, lds_nb, stream>>>(
        ll0, r2, wk[1], wv[1], nullptr, nullptr, nullptr, r1);

    // 5) level 0: x (+r1) + base path -> d_out   (coeff grid 128x128)
    k_convinv<true, 128, 128><<<dim3((128 / JT) * 4, 128, NB), blk, lds_b, stream>>>(
        x, r1, wk[0], wv[0], bk, bb, bs, out);
}

// Round 9
// 746.473 us; speedup vs baseline: 1.1024x; 1.0781x over previous
//
#include <hip/hip_runtime.h>

#define NC 128      // channels
#define NB 8        // batch
#define CPB 32      // channels per block
#define R 4         // consecutive j outputs per thread
#define JT (8 * R)  // j-tile width per block (threadIdx.y covers 8 runs)

// ---------------------------------------------------------------------------
// LL-only Haar downsample: P (NB, 2h, 2w, NC) -> out (NB, h, w, NC)
// ---------------------------------------------------------------------------
__global__ __launch_bounds__(256) void k_haar_ll(
    const float* __restrict__ P, float* __restrict__ out, int h, int w)
{
    int idx = blockIdx.x * blockDim.x + threadIdx.x;
    int total = NB * h * w * (NC / 4);
    if (idx >= total) return;
    int cq = idx & (NC / 4 - 1);
    int t  = idx / (NC / 4);
    int j  = t % w; t /= w;
    int i  = t % h;
    int b  = t / h;
    size_t W2C  = (size_t)(2 * w) * NC;
    size_t base = (((size_t)b * (2 * h) + 2 * i) * (2 * w) + 2 * j) * NC + cq * 4;
    float4 A  = *(const float4*)(P + base);
    float4 Bv = *(const float4*)(P + base + NC);
    float4 Cv = *(const float4*)(P + base + W2C);
    float4 Dv = *(const float4*)(P + base + W2C + NC);
    float4 r;
    r.x = (A.x + Bv.x + Cv.x + Dv.x) * 0.5f;
    r.y = (A.y + Bv.y + Cv.y + Dv.y) * 0.5f;
    r.z = (A.z + Bv.z + Cv.z + Dv.z) * 0.5f;
    r.w = (A.w + Bv.w + Cv.w + Dv.w) * 0.5f;
    *(float4*)(out + (size_t)idx * 4) = r;
}

// ---------------------------------------------------------------------------
// Fused conv-on-haar-subbands + inverse (+ base depthwise for level 0).
// R=4 sliding window + template H/W (compile-time strides) + interior/edge
// split (no coff/cmask arrays). Register budget from measured points:
// R6 (R=4, runtime hw, no split) = 132 VGPR; split -16, templates -15
// => ~105 expected, under the 128 cliff.
// NO (256,4) launch-bounds: it forced a 64-VGPR target and catastrophic
// spills (R4: WRITE 2.4GB, R7: 707MB). (256,2) is a >=128 cap / no-op.
// blockDim = (32, 8). grid = ((W/JT)*4, H, NB). blockIdx.x = jtile*4 + cg.
// ---------------------------------------------------------------------------
#define WL(s, t)  wl[((s) * 25 + (t)) * CPB + tc]
#define WB(m, n)  wbase[((m) * 5 + (n)) * CPB + tc]

template <bool BASE, int H, int W>
__global__ __launch_bounds__(256, 2) void k_convinv(
    const float* __restrict__ P, const float* __restrict__ nll,
    const float* __restrict__ wk, const float* __restrict__ wsc,
    const float* __restrict__ bk, const float* __restrict__ bb,
    const float* __restrict__ bs, float* __restrict__ out)
{
    extern __shared__ float lds[];
    float* wl     = lds;               // [4][25][CPB]
    float* wbase  = wl + 4 * 25 * CPB; // [25][CPB]   (BASE)
    float* bscale = wbase + 25 * CPB;  // [CPB]       (BASE)
    float* bbias  = bscale + CPB;      // [CPB]       (BASE)

    const int cg    = blockIdx.x & 3;
    const int jtile = blockIdx.x >> 2;
    const int c0    = cg * CPB;
    const int tid   = threadIdx.x + threadIdx.y * 32;

    for (int u = tid; u < 4 * 25 * CPB; u += 256) {
        int tcc = u & (CPB - 1);
        int st  = u / CPB;
        int t   = st % 25;
        int s   = st / 25;
        wl[u] = 0.5f * wsc[(c0 + tcc) * 4 + s] * wk[t * (4 * NC) + (c0 + tcc) * 4 + s];
    }
    if (BASE) {
        for (int u = tid; u < 25 * CPB; u += 256) {
            int tcc = u & (CPB - 1);
            int t   = u / CPB;
            wbase[u] = bk[t * NC + c0 + tcc];
        }
        if (tid < CPB) { bscale[tid] = bs[c0 + tid]; bbias[tid] = bb[c0 + tid]; }
    }
    __syncthreads();

    const int tc = threadIdx.x;
    const int c  = c0 + tc;
    const int b  = blockIdx.z;
    const int i  = blockIdx.y;
    const int ja = jtile * JT + threadIdx.y * R;   // first output j of thread
    constexpr int ROWC = 2 * W * NC;               // parent row stride (elems)

    float acc0[R], acc1[R], acc2[R], acc3[R];
    float bb00[R], bb01[R], bb10[R], bb11[R];
    #pragma unroll
    for (int s = 0; s < R; ++s) {
        acc0[s] = acc1[s] = acc2[s] = acc3[s] = 0.f;
        bb00[s] = bb01[s] = bb10[s] = bb11[s] = 0.f;
    }

    const bool interior = (ja >= 2) && (ja <= W - R - 2);

    if (interior) {
        // ------------------------- fast path (no masks) -------------------
        #pragma unroll
        for (int ky = 0; ky < 5; ++ky) {
            int y = i + ky - 2;
            if (y < 0 || y >= H) continue;          // block-uniform

            float w0[5], w1[5], w2[5], w3[5];
            #pragma unroll
            for (int kx = 0; kx < 5; ++kx) {
                const int t = ky * 5 + kx;
                w0[kx] = WL(0, t); w1[kx] = WL(1, t);
                w2[kx] = WL(2, t); w3[kx] = WL(3, t);
            }
            float wbr[3][5];
            if (BASE && ky >= 1 && ky <= 3) {
                #pragma unroll
                for (int n = 0; n < 5; ++n) {
                    if (ky >= 2) wbr[0][n] = WB(2 * ky - 3, n);
                    wbr[1][n] = WB(2 * ky - 2, n);
                    if (ky <= 2) wbr[2][n] = WB(2 * ky - 1, n);
                }
            }

            const float* pA0 = P + (size_t)(b * 2 * H + 2 * y) * ROWC
                                 + (ja - 2) * (2 * NC) + c;
            const float* pC0 = pA0 + ROWC;
            #pragma unroll
            for (int q = 0; q < R + 4; ++q) {
                float A  = pA0[q * 2 * NC];
                float Bv = pA0[q * 2 * NC + NC];
                float Cv = pC0[q * 2 * NC];
                float Dv = pC0[q * 2 * NC + NC];
                float sA = A + Bv, sC = Cv + Dv;
                float dA = A - Bv, dC = Cv - Dv;
                float s0 = sA + sC, s1 = sA - sC, s2 = dA + dC, s3 = dA - dC;
                #pragma unroll
                for (int s = 0; s < R; ++s) {
                    const int kx = q - s;
                    if (kx < 0 || kx > 4) continue;
                    acc0[s] += s0 * w0[kx];
                    acc1[s] += s1 * w1[kx];
                    acc2[s] += s2 * w2[kx];
                    acc3[s] += s3 * w3[kx];
                    if (BASE && ky >= 1 && ky <= 3 && kx >= 1 && kx <= 3) {
                        bb00[s] += A * wbr[1][2 * kx - 2];
                        if (kx >= 2)            bb01[s] += A  * wbr[1][2 * kx - 3];
                        if (ky >= 2)            bb10[s] += A  * wbr[0][2 * kx - 2];
                        if (ky >= 2 && kx >= 2) bb11[s] += A  * wbr[0][2 * kx - 3];
                        if (kx <= 2)            bb00[s] += Bv * wbr[1][2 * kx - 1];
                                                bb01[s] += Bv * wbr[1][2 * kx - 2];
                        if (ky >= 2 && kx <= 2) bb10[s] += Bv * wbr[0][2 * kx - 1];
                        if (ky >= 2)            bb11[s] += Bv * wbr[0][2 * kx - 2];
                        if (ky <= 2)            bb00[s] += Cv * wbr[2][2 * kx - 2];
                        if (ky <= 2 && kx >= 2) bb01[s] += Cv * wbr[2][2 * kx - 3];
                                                bb10[s] += Cv * wbr[1][2 * kx - 2];
                        if (kx >= 2)            bb11[s] += Cv * wbr[1][2 * kx - 3];
                        if (ky <= 2 && kx <= 2) bb00[s] += Dv * wbr[2][2 * kx - 1];
                        if (ky <= 2)            bb01[s] += Dv * wbr[2][2 * kx - 2];
                        if (kx <= 2)            bb10[s] += Dv * wbr[1][2 * kx - 1];
                                                bb11[s] += Dv * wbr[1][2 * kx - 2];
                    }
                }
            }
        }
    } else {
        // ------------------------- edge slow path -------------------------
        #pragma unroll
        for (int s = 0; s < R; ++s) {
            int j = ja + s;
            #pragma unroll
            for (int ky = 0; ky < 5; ++ky) {
                int y = i + ky - 2;
                if (y < 0 || y >= H) continue;
                const float* prA = P + (size_t)(b * 2 * H + 2 * y) * ROWC + c;
                const float* prC = prA + ROWC;
                #pragma unroll
                for (int kx = 0; kx < 5; ++kx) {
                    int xq = j + kx - 2;
                    if (xq < 0 || xq >= W) continue;
                    const float* pA = prA + xq * (2 * NC);
                    const float* pC = prC + xq * (2 * NC);
                    float A  = pA[0];
                    float Bv = pA[NC];
                    float Cv = pC[0];
                    float Dv = pC[NC];
                    float sA = A + Bv, sC = Cv + Dv;
                    float dA = A - Bv, dC = Cv - Dv;
                    const int t = ky * 5 + kx;
                    acc0[s] += (sA + sC) * WL(0, t);
                    acc1[s] += (sA - sC) * WL(1, t);
                    acc2[s] += (dA + dC) * WL(2, t);
                    acc3[s] += (dA - dC) * WL(3, t);
                    if (BASE && ky >= 1 && ky <= 3 && kx >= 1 && kx <= 3) {
                        bb00[s] += A * WB(2 * ky - 2, 2 * kx - 2);
                        if (kx >= 2)            bb01[s] += A  * WB(2 * ky - 2, 2 * kx - 3);
                        if (ky >= 2)            bb10[s] += A  * WB(2 * ky - 3, 2 * kx - 2);
                        if (ky >= 2 && kx >= 2) bb11[s] += A  * WB(2 * ky - 3, 2 * kx - 3);
                        if (kx <= 2)            bb00[s] += Bv * WB(2 * ky - 2, 2 * kx - 1);
                                                bb01[s] += Bv * WB(2 * ky - 2, 2 * kx - 2);
                        if (ky >= 2 && kx <= 2) bb10[s] += Bv * WB(2 * ky - 3, 2 * kx - 1);
                        if (ky >= 2)            bb11[s] += Bv * WB(2 * ky - 3, 2 * kx - 2);
                        if (ky <= 2)            bb00[s] += Cv * WB(2 * ky - 1, 2 * kx - 2);
                        if (ky <= 2 && kx >= 2) bb01[s] += Cv * WB(2 * ky - 1, 2 * kx - 3);
                                                bb10[s] += Cv * WB(2 * ky - 2, 2 * kx - 2);
                        if (kx >= 2)            bb11[s] += Cv * WB(2 * ky - 2, 2 * kx - 3);
                        if (ky <= 2 && kx <= 2) bb00[s] += Dv * WB(2 * ky - 1, 2 * kx - 1);
                        if (ky <= 2)            bb01[s] += Dv * WB(2 * ky - 1, 2 * kx - 2);
                        if (kx <= 2)            bb10[s] += Dv * WB(2 * ky - 2, 2 * kx - 1);
                                                bb11[s] += Dv * WB(2 * ky - 2, 2 * kx - 2);
                    }
                }
            }
        }
    }

    // ------------------------------ epilogue ------------------------------
    #pragma unroll
    for (int s = 0; s < R; ++s) {
        int j = ja + s;
        float a0 = acc0[s];
        if (nll) a0 += nll[((size_t)(b * H + i) * W + j) * NC + c];
        float av = (a0 + acc1[s] + acc2[s] + acc3[s]) * 0.5f;
        float bv = (a0 + acc1[s] - acc2[s] - acc3[s]) * 0.5f;
        float cv = (a0 - acc1[s] + acc2[s] - acc3[s]) * 0.5f;
        float dv = (a0 - acc1[s] - acc2[s] + acc3[s]) * 0.5f;

        size_t ob = (size_t)(b * 2 * H + 2 * i) * (2 * W * NC) + (2 * j) * NC + c;
        if (BASE) {
            float sc = bscale[tc], bi = bbias[tc];
            out[ob]                   = sc * (bb00[s] + bi) + av;
            out[ob + NC]              = sc * (bb01[s] + bi) + bv;
            out[ob + 2 * W * NC]      = sc * (bb10[s] + bi) + cv;
            out[ob + 2 * W * NC + NC] = sc * (bb11[s] + bi) + dv;
        } else {
            out[ob]                   = av;
            out[ob + NC]              = bv;
            out[ob + 2 * W * NC]      = cv;
            out[ob + 2 * W * NC + NC] = dv;
        }
    }
}

// ---------------------------------------------------------------------------
extern "C" void kernel_launch(void* const* d_in, const int* in_sizes, int n_in,
                              void* d_out, int out_size, void* d_ws, size_t ws_size,
                              hipStream_t stream)
{
    const float* x  = (const float*)d_in[0];
    const float* bk = (const float*)d_in[1];
    const float* bb = (const float*)d_in[2];
    const float* bs = (const float*)d_in[3];
    const float* wk[3];
    const float* wv[3];
    if (n_in >= 10) {
        for (int i = 0; i < 3; ++i) {
            wk[i] = (const float*)d_in[4 + i];
            wv[i] = (const float*)d_in[7 + i];
        }
    } else {
        const float* wkc = (const float*)d_in[4];
        const float* wvc = (const float*)d_in[5];
        for (int i = 0; i < 3; ++i) {
            wk[i] = wkc + (size_t)i * 25 * 4 * NC;
            wv[i] = wvc + (size_t)i * 4 * NC;
        }
    }
    float* out = (float*)d_out;

    // Dead-before-final intermediates live inside d_out (fully rewritten by
    // the final kernel). r1 (read during final pass) lives in d_ws.
    float* ll0 = out;                       // (8,128,128,128)
    float* ll1 = out + 16777216;            // (8, 64, 64,128)
    float* r2  = out + 16777216 + 4194304;  // (8, 64, 64,128)
    float* r1  = (float*)d_ws;              // (8,128,128,128) = 64 MiB

    // 1) x -> ll0
    {
        int total = NB * 128 * 128 * (NC / 4);
        k_haar_ll<<<(total + 255) / 256, 256, 0, stream>>>(x, ll0, 128, 128);
    }
    // 2) ll0 -> ll1
    {
        int total = NB * 64 * 64 * (NC / 4);
        k_haar_ll<<<(total + 255) / 256, 256, 0, stream>>>(ll0, ll1, 64, 64);
    }

    size_t lds_nb = (size_t)(4 * 25 * CPB) * sizeof(float);                      // 12800 B
    size_t lds_b  = (size_t)(4 * 25 * CPB + 25 * CPB + 2 * CPB) * sizeof(float); // 16256 B
    dim3 blk(32, 8);

    // 3) level 2: ll1 -> r2   (coeff grid 32x32)
    k_convinv<false, 32, 32><<<dim3((32 / JT) * 4, 32, NB), blk, lds_nb, stream>>>(
        ll1, nullptr, wk[2], wv[2], nullptr, nullptr, nullptr, r2);

    // 4) level 1: ll0 (+r2) -> r1   (coeff grid 64x64)
    k_convinv<false, 64, 64><<<dim3((64 / JT) * 4, 64, NB), blk, lds_nb, stream>>>(
        ll0, r2, wk[1], wv[1], nullptr, nullptr, nullptr, r1);

    // 5) level 0: x (+r1) + base path -> d_out   (coeff grid 128x128)
    k_convinv<true, 128, 128><<<dim3((128 / JT) * 4, 128, NB), blk, lds_b, stream>>>(
        x, r1, wk[0], wv[0], bk, bb, bs, out);
}

// Round 10
// 646.275 us; speedup vs baseline: 1.2733x; 1.1550x over previous
//
#include <hip/hip_runtime.h>

#define NC 128      // channels
#define NB 8        // batch
#define CPB 32      // channels per block = 16 lanes x float2
#define R 2         // consecutive j outputs per thread
#define JT 32       // j-tile width per block (threadIdx.y = 16 slots x R)

__device__ __forceinline__ float2 ld2(const float* p) { return *(const float2*)p; }
__device__ __forceinline__ float2 add2(float2 a, float2 b) { return make_float2(a.x + b.x, a.y + b.y); }
__device__ __forceinline__ float2 sub2(float2 a, float2 b) { return make_float2(a.x - b.x, a.y - b.y); }
__device__ __forceinline__ float2 muls2(float2 a, float s) { return make_float2(a.x * s, a.y * s); }
__device__ __forceinline__ float2 fma2(float2 a, float2 w, float2 c) {
    return make_float2(fmaf(a.x, w.x, c.x), fmaf(a.y, w.y, c.y));
}

// ---------------------------------------------------------------------------
// LL-only Haar downsample: P (NB, 2h, 2w, NC) -> out (NB, h, w, NC)
// ---------------------------------------------------------------------------
__global__ __launch_bounds__(256) void k_haar_ll(
    const float* __restrict__ P, float* __restrict__ out, int h, int w)
{
    int idx = blockIdx.x * blockDim.x + threadIdx.x;
    int total = NB * h * w * (NC / 4);
    if (idx >= total) return;
    int cq = idx & (NC / 4 - 1);
    int t  = idx / (NC / 4);
    int j  = t % w; t /= w;
    int i  = t % h;
    int b  = t / h;
    size_t W2C  = (size_t)(2 * w) * NC;
    size_t base = (((size_t)b * (2 * h) + 2 * i) * (2 * w) + 2 * j) * NC + cq * 4;
    float4 A  = *(const float4*)(P + base);
    float4 Bv = *(const float4*)(P + base + NC);
    float4 Cv = *(const float4*)(P + base + W2C);
    float4 Dv = *(const float4*)(P + base + W2C + NC);
    float4 r;
    r.x = (A.x + Bv.x + Cv.x + Dv.x) * 0.5f;
    r.y = (A.y + Bv.y + Cv.y + Dv.y) * 0.5f;
    r.z = (A.z + Bv.z + Cv.z + Dv.z) * 0.5f;
    r.w = (A.w + Bv.w + Cv.w + Dv.w) * 0.5f;
    *(float4*)(out + (size_t)idx * 4) = r;
}

// ---------------------------------------------------------------------------
// Fused conv-on-haar-subbands + inverse (+ base depthwise for level 0).
// R5 structure (masked sliding window, runtime h/w, no launch-bounds cap)
// vectorized to float2 channels: 16 lanes x 2ch, halves loads/addressing/
// LDS-weight reads per unit; arithmetic can pack into v_pk_fma_f32.
// Weights read directly from LDS (float2 staging would cost 70+ VGPR).
// blockDim = (16,16). grid = ((w/JT)*4, h, NB). blockIdx.x = jtile*4 + cg.
// ---------------------------------------------------------------------------
#define WL2(s, t)  (wl + ((s) * 25 + (t)) * CPB + 2 * tc)
#define WB2(m, n)  (wbase + ((m) * 5 + (n)) * CPB + 2 * tc)

template <bool BASE>
__global__ __launch_bounds__(256) void k_convinv(
    const float* __restrict__ P, const float* __restrict__ nll,
    const float* __restrict__ wk, const float* __restrict__ wsc,
    const float* __restrict__ bk, const float* __restrict__ bb,
    const float* __restrict__ bs, float* __restrict__ out,
    int h, int w)
{
    extern __shared__ float lds[];
    float* wl     = lds;               // [4][25][CPB]
    float* wbase  = wl + 4 * 25 * CPB; // [25][CPB]   (BASE)
    float* bscale = wbase + 25 * CPB;  // [CPB]       (BASE)
    float* bbias  = bscale + CPB;      // [CPB]       (BASE)

    const int cg    = blockIdx.x & 3;
    const int jtile = blockIdx.x >> 2;
    const int c0    = cg * CPB;
    const int tid   = threadIdx.x + threadIdx.y * 16;

    for (int u = tid; u < 4 * 25 * CPB; u += 256) {
        int tcc = u & (CPB - 1);
        int st  = u / CPB;
        int t   = st % 25;
        int s   = st / 25;
        wl[u] = 0.5f * wsc[(c0 + tcc) * 4 + s] * wk[t * (4 * NC) + (c0 + tcc) * 4 + s];
    }
    if (BASE) {
        for (int u = tid; u < 25 * CPB; u += 256) {
            int tcc = u & (CPB - 1);
            int t   = u / CPB;
            wbase[u] = bk[t * NC + c0 + tcc];
        }
        if (tid < CPB) { bscale[tid] = bs[c0 + tid]; bbias[tid] = bb[c0 + tid]; }
    }
    __syncthreads();

    const int tc = threadIdx.x;        // 0..15 (channel-pair lane)
    const int cc = c0 + 2 * tc;        // first channel of this lane's pair
    const int b  = blockIdx.z;
    const int i  = blockIdx.y;
    const int ja = jtile * JT + threadIdx.y * R;   // first output j of thread
    const int PH = 2 * h;
    const size_t rowC = (size_t)(2 * w) * NC;

    // Per-column clamped element offsets + validity masks (col = ja + q - 2).
    int   coff[R + 4];
    float cmask[R + 4];
    #pragma unroll
    for (int q = 0; q < R + 4; ++q) {
        int xq  = ja + q - 2;
        int xqc = min(max(xq, 0), w - 1);
        coff[q]  = xqc * (2 * NC);
        cmask[q] = (xq >= 0 && xq < w) ? 1.f : 0.f;
    }

    float2 acc0[R], acc1[R], acc2[R], acc3[R];
    float2 bb00[R], bb01[R], bb10[R], bb11[R];
    #pragma unroll
    for (int s = 0; s < R; ++s) {
        acc0[s] = acc1[s] = acc2[s] = acc3[s] = make_float2(0.f, 0.f);
        bb00[s] = bb01[s] = bb10[s] = bb11[s] = make_float2(0.f, 0.f);
    }

    #pragma unroll
    for (int ky = 0; ky < 5; ++ky) {
        int y = i + ky - 2;
        if (y < 0 || y >= h) continue;          // block-uniform branch

        const float* prA = P + ((size_t)b * PH + 2 * y) * rowC + cc;
        const float* prC = prA + rowC;
        #pragma unroll
        for (int q = 0; q < R + 4; ++q) {
            float m = cmask[q];
            const float* pA = prA + coff[q];
            const float* pC = prC + coff[q];
            float2 A  = muls2(ld2(pA), m);
            float2 Bv = muls2(ld2(pA + NC), m);
            float2 Cv = muls2(ld2(pC), m);
            float2 Dv = muls2(ld2(pC + NC), m);
            float2 sA = add2(A, Bv), sC = add2(Cv, Dv);
            float2 dA = sub2(A, Bv), dC = sub2(Cv, Dv);
            float2 s0 = add2(sA, sC), s1 = sub2(sA, sC);
            float2 s2 = add2(dA, dC), s3 = sub2(dA, dC);
            #pragma unroll
            for (int s = 0; s < R; ++s) {
                const int kx = q - s;          // tap index for output s
                if (kx < 0 || kx > 4) continue;
                const int t = ky * 5 + kx;
                acc0[s] = fma2(s0, ld2(WL2(0, t)), acc0[s]);
                acc1[s] = fma2(s1, ld2(WL2(1, t)), acc1[s]);
                acc2[s] = fma2(s2, ld2(WL2(2, t)), acc2[s]);
                acc3[s] = fma2(s3, ld2(WL2(3, t)), acc3[s]);
                if (BASE && ky >= 1 && ky <= 3 && kx >= 1 && kx <= 3) {
                    bb00[s] = fma2(A, ld2(WB2(2 * ky - 2, 2 * kx - 2)), bb00[s]);
                    if (kx >= 2)            bb01[s] = fma2(A,  ld2(WB2(2 * ky - 2, 2 * kx - 3)), bb01[s]);
                    if (ky >= 2)            bb10[s] = fma2(A,  ld2(WB2(2 * ky - 3, 2 * kx - 2)), bb10[s]);
                    if (ky >= 2 && kx >= 2) bb11[s] = fma2(A,  ld2(WB2(2 * ky - 3, 2 * kx - 3)), bb11[s]);
                    if (kx <= 2)            bb00[s] = fma2(Bv, ld2(WB2(2 * ky - 2, 2 * kx - 1)), bb00[s]);
                                            bb01[s] = fma2(Bv, ld2(WB2(2 * ky - 2, 2 * kx - 2)), bb01[s]);
                    if (ky >= 2 && kx <= 2) bb10[s] = fma2(Bv, ld2(WB2(2 * ky - 3, 2 * kx - 1)), bb10[s]);
                    if (ky >= 2)            bb11[s] = fma2(Bv, ld2(WB2(2 * ky - 3, 2 * kx - 2)), bb11[s]);
                    if (ky <= 2)            bb00[s] = fma2(Cv, ld2(WB2(2 * ky - 1, 2 * kx - 2)), bb00[s]);
                    if (ky <= 2 && kx >= 2) bb01[s] = fma2(Cv, ld2(WB2(2 * ky - 1, 2 * kx - 3)), bb01[s]);
                                            bb10[s] = fma2(Cv, ld2(WB2(2 * ky - 2, 2 * kx - 2)), bb10[s]);
                    if (kx >= 2)            bb11[s] = fma2(Cv, ld2(WB2(2 * ky - 2, 2 * kx - 3)), bb11[s]);
                    if (ky <= 2 && kx <= 2) bb00[s] = fma2(Dv, ld2(WB2(2 * ky - 1, 2 * kx - 1)), bb00[s]);
                    if (ky <= 2)            bb01[s] = fma2(Dv, ld2(WB2(2 * ky - 1, 2 * kx - 2)), bb01[s]);
                    if (kx <= 2)            bb10[s] = fma2(Dv, ld2(WB2(2 * ky - 2, 2 * kx - 1)), bb10[s]);
                                            bb11[s] = fma2(Dv, ld2(WB2(2 * ky - 2, 2 * kx - 2)), bb11[s]);
                }
            }
        }
    }

    // ------------------------------ epilogue ------------------------------
    #pragma unroll
    for (int s = 0; s < R; ++s) {
        int j = ja + s;
        float2 a0 = acc0[s];
        if (nll) a0 = add2(a0, ld2(nll + (((size_t)b * h + i) * w + j) * NC + cc));
        float2 av = muls2(add2(add2(a0, acc1[s]), add2(acc2[s], acc3[s])), 0.5f);
        float2 bv = muls2(sub2(add2(a0, acc1[s]), add2(acc2[s], acc3[s])), 0.5f);
        float2 cv = muls2(add2(sub2(a0, acc1[s]), sub2(acc2[s], acc3[s])), 0.5f);
        float2 dv = muls2(sub2(sub2(a0, acc1[s]), sub2(acc2[s], acc3[s])), 0.5f);

        size_t ob = ((size_t)b * PH + 2 * i) * rowC + (size_t)(2 * j) * NC + cc;
        if (BASE) {
            float2 sc = ld2(bscale + 2 * tc);
            float2 bi = ld2(bbias + 2 * tc);
            float2 o00 = add2(make_float2(sc.x * (bb00[s].x + bi.x), sc.y * (bb00[s].y + bi.y)), av);
            float2 o01 = add2(make_float2(sc.x * (bb01[s].x + bi.x), sc.y * (bb01[s].y + bi.y)), bv);
            float2 o10 = add2(make_float2(sc.x * (bb10[s].x + bi.x), sc.y * (bb10[s].y + bi.y)), cv);
            float2 o11 = add2(make_float2(sc.x * (bb11[s].x + bi.x), sc.y * (bb11[s].y + bi.y)), dv);
            *(float2*)(out + ob)             = o00;
            *(float2*)(out + ob + NC)        = o01;
            *(float2*)(out + ob + rowC)      = o10;
            *(float2*)(out + ob + rowC + NC) = o11;
        } else {
            *(float2*)(out + ob)             = av;
            *(float2*)(out + ob + NC)        = bv;
            *(float2*)(out + ob + rowC)      = cv;
            *(float2*)(out + ob + rowC + NC) = dv;
        }
    }
}

// ---------------------------------------------------------------------------
extern "C" void kernel_launch(void* const* d_in, const int* in_sizes, int n_in,
                              void* d_out, int out_size, void* d_ws, size_t ws_size,
                              hipStream_t stream)
{
    const float* x  = (const float*)d_in[0];
    const float* bk = (const float*)d_in[1];
    const float* bb = (const float*)d_in[2];
    const float* bs = (const float*)d_in[3];
    const float* wk[3];
    const float* wv[3];
    if (n_in >= 10) {
        for (int i = 0; i < 3; ++i) {
            wk[i] = (const float*)d_in[4 + i];
            wv[i] = (const float*)d_in[7 + i];
        }
    } else {
        const float* wkc = (const float*)d_in[4];
        const float* wvc = (const float*)d_in[5];
        for (int i = 0; i < 3; ++i) {
            wk[i] = wkc + (size_t)i * 25 * 4 * NC;
            wv[i] = wvc + (size_t)i * 4 * NC;
        }
    }
    float* out = (float*)d_out;

    // Dead-before-final intermediates live inside d_out (fully rewritten by
    // the final kernel). r1 (read during final pass) lives in d_ws.
    float* ll0 = out;                       // (8,128,128,128)
    float* ll1 = out + 16777216;            // (8, 64, 64,128)
    float* r2  = out + 16777216 + 4194304;  // (8, 64, 64,128)
    float* r1  = (float*)d_ws;              // (8,128,128,128) = 64 MiB

    // 1) x -> ll0
    {
        int total = NB * 128 * 128 * (NC / 4);
        k_haar_ll<<<(total + 255) / 256, 256, 0, stream>>>(x, ll0, 128, 128);
    }
    // 2) ll0 -> ll1
    {
        int total = NB * 64 * 64 * (NC / 4);
        k_haar_ll<<<(total + 255) / 256, 256, 0, stream>>>(ll0, ll1, 64, 64);
    }

    size_t lds_nb = (size_t)(4 * 25 * CPB) * sizeof(float);                      // 12800 B
    size_t lds_b  = (size_t)(4 * 25 * CPB + 25 * CPB + 2 * CPB) * sizeof(float); // 16256 B
    dim3 blk(16, 16);

    // 3) level 2: ll1 -> r2   (coeff grid 32x32)
    k_convinv<false><<<dim3((32 / JT) * 4, 32, NB), blk, lds_nb, stream>>>(
        ll1, nullptr, wk[2], wv[2], nullptr, nullptr, nullptr, r2, 32, 32);

    // 4) level 1: ll0 (+r2) -> r1   (coeff grid 64x64)
    k_convinv<false><<<dim3((64 / JT) * 4, 64, NB), blk, lds_nb, stream>>>(
        ll0, r2, wk[1], wv[1], nullptr, nullptr, nullptr, r1, 64, 64);

    // 5) level 0: x (+r1) + base path -> d_out   (coeff grid 128x128)
    k_convinv<true><<<dim3((128 / JT) * 4, 128, NB), blk, lds_b, stream>>>(
        x, r1, wk[0], wv[0], bk, bb, bs, out, 128, 128);
}